// Round 6
// baseline (491.401 us; speedup 1.0000x reference)
//
#include <hip/hip_runtime.h>

#define NBLK 2048
#define BLK  256

// Pass 1: deterministic per-block partial sums in double.
// 64-lane wave shuffle reduce -> LDS -> one partial per block.
__global__ __launch_bounds__(BLK) void partial_sum_kernel(
    const float* __restrict__ x, double* __restrict__ partials, long long n) {
    long long tid    = (long long)blockIdx.x * blockDim.x + threadIdx.x;
    long long stride = (long long)gridDim.x * blockDim.x;
    long long n4     = n >> 2;

    double acc = 0.0;
    const float4* __restrict__ x4 = (const float4*)x;
    for (long long i = tid; i < n4; i += stride) {
        float4 v = x4[i];
        acc += (double)v.x + (double)v.y + (double)v.z + (double)v.w;
    }
    // tail (n not multiple of 4) — empty for 64M but keep general
    for (long long i = (n4 << 2) + tid; i < n; i += stride) acc += (double)x[i];

    // wave64 butterfly
    for (int off = 32; off > 0; off >>= 1)
        acc += __shfl_down(acc, off, 64);

    __shared__ double sdata[BLK / 64];
    int lane = threadIdx.x & 63;
    int wid  = threadIdx.x >> 6;
    if (lane == 0) sdata[wid] = acc;
    __syncthreads();
    if (threadIdx.x == 0) {
        double s = 0.0;
        #pragma unroll
        for (int i = 0; i < BLK / 64; ++i) s += sdata[i];
        partials[blockIdx.x] = s;
    }
}

// Pass 2: single block folds the 2048 partials and computes the scalar
// total = n*(n-1)/2 if n>1 else 0, with n = trunc(sum).
__global__ __launch_bounds__(256) void final_reduce_kernel(
    const double* __restrict__ partials, float* __restrict__ total, int nblk) {
    double acc = 0.0;
    for (int i = threadIdx.x; i < nblk; i += blockDim.x) acc += partials[i];
    for (int off = 32; off > 0; off >>= 1)
        acc += __shfl_down(acc, off, 64);

    __shared__ double sdata[4];
    int lane = threadIdx.x & 63;
    int wid  = threadIdx.x >> 6;
    if (lane == 0) sdata[wid] = acc;
    __syncthreads();
    if (threadIdx.x == 0) {
        double s = sdata[0] + sdata[1] + sdata[2] + sdata[3];
        double nn = trunc(s);                       // int() truncates toward zero
        double t  = (nn > 1.0) ? nn * (nn - 1.0) * 0.5 : 0.0;
        *total = (float)t;                          // ref does the add in fp32
    }
}

// Pass 3: out = x + total, vectorized.
__global__ __launch_bounds__(BLK) void add_kernel(
    const float* __restrict__ x, float* __restrict__ out,
    const float* __restrict__ total, long long n) {
    float t = *total;   // uniform scalar, L2-broadcast
    long long tid    = (long long)blockIdx.x * blockDim.x + threadIdx.x;
    long long stride = (long long)gridDim.x * blockDim.x;
    long long n4     = n >> 2;

    const float4* __restrict__ x4 = (const float4*)x;
    float4* __restrict__ o4       = (float4*)out;
    for (long long i = tid; i < n4; i += stride) {
        float4 v = x4[i];
        v.x += t; v.y += t; v.z += t; v.w += t;
        o4[i] = v;
    }
    for (long long i = (n4 << 2) + tid; i < n; i += stride) out[i] = x[i] + t;
}

extern "C" void kernel_launch(void* const* d_in, const int* in_sizes, int n_in,
                              void* d_out, int out_size, void* d_ws, size_t ws_size,
                              hipStream_t stream) {
    const float* x = (const float*)d_in[0];
    float* out     = (float*)d_out;
    long long n    = (long long)in_sizes[0];

    // Workspace layout: [NBLK doubles partials][1 float total]
    double* partials = (double*)d_ws;
    float*  total    = (float*)(partials + NBLK);

    partial_sum_kernel<<<NBLK, BLK, 0, stream>>>(x, partials, n);
    final_reduce_kernel<<<1, 256, 0, stream>>>(partials, total, NBLK);
    add_kernel<<<NBLK, BLK, 0, stream>>>(x, out, total, n);
}